// Round 5
// baseline (74.273 us; speedup 1.0000x reference)
//
#include <hip/hip_runtime.h>
#include <math.h>

typedef __attribute__((ext_vector_type(8))) short short8;
typedef __attribute__((ext_vector_type(4))) float f32x4;
typedef __attribute__((ext_vector_type(8))) unsigned short u16x8;

#define TAUF 32.0f

// LDS: two B double-buffer halves; C epilogue tile overlays the same space.
constexpr int B_LO_OFF = 12288;  // lo plane offset within a buffer half
constexpr int BUF_SZ   = 24576;  // one half: 192 cols x 32 k x 2 planes x 2B
constexpr int CSTR     = 196;    // epilogue C row stride (floats)

// ---------------------------------------------------------------------------
// Kernel 1: PR rows = memory[dm] . W  (rows 0..89: W_topic; 90..179: W_domain)
// as split-bf16 planes PRhi/PRlo [192][768]; rows 180..191 zeroed.
// grid 32 x 768 threads: block owns 6 PR rows (one W side each, 90%6==0),
// thread t owns col t. W re-read cut 3x vs 2-row version.
// ---------------------------------------------------------------------------
__global__ __launch_bounds__(768) void precompute_pr(
    const float* __restrict__ Wt, const float* __restrict__ Wd,
    const float* __restrict__ mem, unsigned short* __restrict__ PRhi,
    unsigned short* __restrict__ PRlo) {
  int r0 = blockIdx.x * 6, t = threadIdx.x;
  if (r0 >= 180) {
    #pragma unroll
    for (int rr = 0; rr < 6; ++rr) {
      PRhi[(size_t)(r0 + rr) * 768 + t] = 0;
      PRlo[(size_t)(r0 + rr) * 768 + t] = 0;
    }
    return;
  }
  __shared__ float mlds[1536];
  const float* W = (r0 >= 90) ? Wd : Wt;
  int dm0 = (r0 >= 90) ? r0 - 90 : r0;
  for (int i = t; i < 1536; i += 768) mlds[i] = mem[(size_t)dm0 * 256 + i];
  __syncthreads();
  float a[6] = {0.f, 0.f, 0.f, 0.f, 0.f, 0.f};
  #pragma unroll 4
  for (int e = 0; e < 256; ++e) {
    float w = W[(size_t)e * 768 + t];
    #pragma unroll
    for (int rr = 0; rr < 6; ++rr) a[rr] += mlds[rr * 256 + e] * w;
  }
  #pragma unroll
  for (int rr = 0; rr < 6; ++rr) {
    unsigned int bu = __float_as_uint(a[rr]);
    unsigned short hi = (unsigned short)(bu >> 16);
    float hf = __uint_as_float(bu & 0xffff0000u);
    unsigned short lo = (unsigned short)(__float_as_uint(a[rr] - hf) >> 16);
    PRhi[(size_t)(r0 + rr) * 768 + t] = hi;
    PRlo[(size_t)(r0 + rr) * 768 + t] = lo;
  }
}

// ---------------------------------------------------------------------------
// Kernel 2: fused split-bf16 MFMA GEMM [64 rows x 192 cols x K=768] +
// row L2-norm + double softmax. 256 threads = 4 waves (2 rg x 2 cg).
// Counted-vmcnt pipeline (T3/T4): B DMA'd 1 tile ahead (2 buffers), A
// prefetched 2 tiles ahead in regs; never vmcnt(0) in the main loop.
// ---------------------------------------------------------------------------
__global__ __launch_bounds__(256, 2) void fused_mfma(
    const float* __restrict__ feat, const unsigned short* __restrict__ PRhi,
    const unsigned short* __restrict__ PRlo, float* __restrict__ out) {
  __shared__ f32x4 smemv[3136];    // 50176 B: 2x24576 B buffers / C tile
  __shared__ float invn[64];
  __shared__ float sarr[576];
  char* smem = (char*)smemv;

  const int t    = threadIdx.x;
  const int lane = t & 63;
  const int wid  = t >> 6;         // 0..3
  const int rg   = wid >> 1;       // rows rg*32..+31
  const int cg   = wid & 1;        // cols cg*96..+95
  const int b0   = blockIdx.x * 64;

  // ---- A: direct global fragment loads. lane -> row (lane&15), k-chunk
  // (lane>>4)*8 floats. Two rowtiles (+0, +16 rows).
  const float* gA0 = feat + (size_t)(b0 + rg * 32 + (lane & 15)) * 768 +
                     ((lane >> 4) << 3);
  const float* gA1 = gA0 + 16 * 768;

  // ---- B DMA: 24 instrs/ktile (2 planes x 12 col-chunks), 6 per wave.
  // lane l covers (local col c=l>>2, slot s=l&3); slot s stores granule
  // g = s ^ ((c>>1)&3)  -> intra-line permutation, stays coalesced.
  const int iid  = wid * 6;
  const int bc   = lane >> 2;
  const int bsw  = (lane & 3) ^ ((bc >> 1) & 3);
  const int bsrc = bc * 1536 + bsw * 16;

  // ---- B fragment read offset (swizzled, conflict-free)
  const int bfr = ((lane & 15) << 6) |
                  ((((lane >> 4) ^ (((lane & 15) >> 1) & 3)) & 3) << 4);

  f32x4 acc0[6], acc1[6];
  #pragma unroll
  for (int j = 0; j < 6; ++j) {
    acc0[j] = (f32x4){0.f, 0.f, 0.f, 0.f};
    acc1[j] = (f32x4){0.f, 0.f, 0.f, 0.f};
  }
  float ssq0 = 0.f, ssq1 = 0.f;

  auto issueB = [&](int kt, int bb) {
    #pragma unroll
    for (int u = 0; u < 6; ++u) {
      int i  = iid + u;
      int pl = i >= 12;
      int ch = pl ? i - 12 : i;
      const unsigned short* basep = pl ? PRlo : PRhi;
      const char* gg = (const char*)basep + (size_t)ch * 16 * 1536 +
                       kt * 64 + bsrc;
      char* l = smem + bb * BUF_SZ + (pl ? B_LO_OFF : 0) + ch * 1024 +
                lane * 16;
      __builtin_amdgcn_global_load_lds((const unsigned int*)gg,
                                       (unsigned int*)l, 16, 0, 0);
    }
  };

  // two A register sets (named, never runtime-indexed)
  float4 Aa0, Aa1, Aa2, Aa3, Ab0, Ab1, Ab2, Ab3;
  auto loadAa = [&](int kt) {
    Aa0 = *(const float4*)(gA0 + kt * 32);
    Aa1 = *(const float4*)(gA0 + kt * 32 + 4);
    Aa2 = *(const float4*)(gA1 + kt * 32);
    Aa3 = *(const float4*)(gA1 + kt * 32 + 4);
  };
  auto loadAb = [&](int kt) {
    Ab0 = *(const float4*)(gA0 + kt * 32);
    Ab1 = *(const float4*)(gA0 + kt * 32 + 4);
    Ab2 = *(const float4*)(gA1 + kt * 32);
    Ab3 = *(const float4*)(gA1 + kt * 32 + 4);
  };

  short8 ah0, al0, ah1, al1;
  auto cvtCore = [&](float4 ra0a, float4 ra0b, float4 ra1a, float4 ra1b) {
    float x0[8] = {ra0a.x, ra0a.y, ra0a.z, ra0a.w, ra0b.x, ra0b.y, ra0b.z, ra0b.w};
    float x1[8] = {ra1a.x, ra1a.y, ra1a.z, ra1a.w, ra1b.x, ra1b.y, ra1b.z, ra1b.w};
    u16x8 h0, l0, h1, l1;
    #pragma unroll
    for (int e = 0; e < 8; ++e) {
      float x = x0[e];
      ssq0 += x * x;
      unsigned int bu = __float_as_uint(x);
      h0[e] = (unsigned short)(bu >> 16);
      l0[e] = (unsigned short)(__float_as_uint(x - __uint_as_float(bu & 0xffff0000u)) >> 16);
      float y = x1[e];
      ssq1 += y * y;
      unsigned int bv = __float_as_uint(y);
      h1[e] = (unsigned short)(bv >> 16);
      l1[e] = (unsigned short)(__float_as_uint(y - __uint_as_float(bv & 0xffff0000u)) >> 16);
    }
    ah0 = (short8)h0; al0 = (short8)l0; ah1 = (short8)h1; al1 = (short8)l1;
  };

  auto domfma = [&](int bb) {
    char* base = smem + bb * BUF_SZ;
    #pragma unroll
    for (int j = 0; j < 6; ++j) {
      int chb = (cg * 6 + j) * 1024;
      short8 bh = *(const short8*)(base + chb + bfr);
      short8 bl = *(const short8*)(base + B_LO_OFF + chb + bfr);
      acc0[j] = __builtin_amdgcn_mfma_f32_16x16x32_bf16(ah0, bh, acc0[j], 0, 0, 0);
      acc0[j] = __builtin_amdgcn_mfma_f32_16x16x32_bf16(al0, bh, acc0[j], 0, 0, 0);
      acc0[j] = __builtin_amdgcn_mfma_f32_16x16x32_bf16(ah0, bl, acc0[j], 0, 0, 0);
      acc1[j] = __builtin_amdgcn_mfma_f32_16x16x32_bf16(ah1, bh, acc1[j], 0, 0, 0);
      acc1[j] = __builtin_amdgcn_mfma_f32_16x16x32_bf16(al1, bh, acc1[j], 0, 0, 0);
      acc1[j] = __builtin_amdgcn_mfma_f32_16x16x32_bf16(ah1, bl, acc1[j], 0, 0, 0);
    }
  };

  // ---- prologue: B(0)->buf0, B(1)->buf1, A(0)->Aa, A(1)->Ab
  issueB(0, 0);
  issueB(1, 1);
  loadAa(0);
  loadAb(1);
  asm volatile("s_waitcnt vmcnt(14)" ::: "memory");  // B(0) landed (own share)
  __builtin_amdgcn_sched_barrier(0);
  __builtin_amdgcn_s_barrier();                      // B(0) landed globally

  // ---- main loop: 2 ktiles/iter, counted vmcnt, raw barriers
  for (int kp = 0; kp < 11; ++kp) {
    int kt = 2 * kp;
    // even tile kt: compute buf0 with Aa, refill Aa <- kt+2
    cvtCore(Aa0, Aa1, Aa2, Aa3);
    domfma(0);
    __builtin_amdgcn_sched_barrier(0);
    __builtin_amdgcn_s_barrier();                    // all done reading buf0
    issueB(kt + 2, 0);
    loadAa(kt + 2);
    asm volatile("s_waitcnt vmcnt(14)" ::: "memory");  // B(kt+1) landed (own)
    __builtin_amdgcn_sched_barrier(0);
    __builtin_amdgcn_s_barrier();                    // B(kt+1) landed globally
    // odd tile kt+1: compute buf1 with Ab, refill Ab <- kt+3
    cvtCore(Ab0, Ab1, Ab2, Ab3);
    domfma(1);
    __builtin_amdgcn_sched_barrier(0);
    __builtin_amdgcn_s_barrier();                    // all done reading buf1
    issueB(kt + 3, 1);
    loadAb(kt + 3);
    asm volatile("s_waitcnt vmcnt(14)" ::: "memory");  // B(kt+2) landed (own)
    __builtin_amdgcn_sched_barrier(0);
    __builtin_amdgcn_s_barrier();                    // B(kt+2) landed globally
  }
  // tail: kt=22 on buf0 (B(23) already in flight to buf1), then kt=23
  cvtCore(Aa0, Aa1, Aa2, Aa3);
  domfma(0);
  __builtin_amdgcn_sched_barrier(0);
  __builtin_amdgcn_s_barrier();
  asm volatile("s_waitcnt vmcnt(0)" ::: "memory");   // B(23) + A(23) landed
  __builtin_amdgcn_sched_barrier(0);
  __builtin_amdgcn_s_barrier();
  cvtCore(Ab0, Ab1, Ab2, Ab3);
  domfma(1);

  // ---- row L2-norm: lanes l, l+16, l+32, l+48 hold the 4 k-chunk partials
  float v0 = ssq0, v1 = ssq1;
  v0 += __shfl_xor(v0, 16, 64); v0 += __shfl_xor(v0, 32, 64);
  v1 += __shfl_xor(v1, 16, 64); v1 += __shfl_xor(v1, 32, 64);
  if (cg == 0 && lane < 16) {
    invn[rg * 32 + lane]      = rsqrtf(v0);
    invn[rg * 32 + 16 + lane] = rsqrtf(v1);
  }
  __syncthreads();   // invn visible; all MFMA/LDS reads drained -> reuse smem

  // ---- write scaled C (q|r) to LDS
  float* Clds = (float*)smem;
  #pragma unroll
  for (int rt = 0; rt < 2; ++rt) {
    int rbase = rg * 32 + rt * 16 + ((lane >> 4) << 2);
    #pragma unroll
    for (int j = 0; j < 6; ++j) {
      int col = cg * 96 + j * 16 + (lane & 15);
      f32x4 v = rt ? acc1[j] : acc0[j];
      #pragma unroll
      for (int jj = 0; jj < 4; ++jj)
        Clds[(rbase + jj) * CSTR + col] = v[jj] * invn[rbase + jj];
    }
  }
  __syncthreads();

  // ---- per (row,d): softmax over m, dot with r
  for (int pid = t; pid < 576; pid += 256) {
    int row = pid / 9, d = pid - row * 9;
    const float* qp = Clds + row * CSTR + d * 10;
    const float* rp = qp + 90;
    float mx = qp[0];
    #pragma unroll
    for (int m = 1; m < 10; ++m) mx = fmaxf(mx, qp[m]);
    float s = 0.f, val = 0.f;
    #pragma unroll
    for (int m = 0; m < 10; ++m) {
      float e = __expf(TAUF * (qp[m] - mx));
      s += e;
      val += e * rp[m];
    }
    sarr[pid] = val / s;
  }
  __syncthreads();

  // ---- per row: softmax over d, write out
  if (t < 64) {
    float v[9];
    #pragma unroll
    for (int d = 0; d < 9; ++d) v[d] = sarr[t * 9 + d];
    float mx = v[0];
    #pragma unroll
    for (int d = 1; d < 9; ++d) mx = fmaxf(mx, v[d]);
    float s = 0.f;
    float e[9];
    #pragma unroll
    for (int d = 0; d < 9; ++d) {
      e[d] = __expf(TAUF * (v[d] - mx));
      s += e[d];
    }
    float is = 1.f / s;
    #pragma unroll
    for (int d = 0; d < 9; ++d)
      out[(size_t)(b0 + t) * 9 + d] = e[d] * is;
  }
}

extern "C" void kernel_launch(void* const* d_in, const int* in_sizes, int n_in,
                              void* d_out, int out_size, void* d_ws, size_t ws_size,
                              hipStream_t stream) {
  const float* feat = (const float*)d_in[0];
  // d_in[1] = category (unused by forward math)
  const float* Wt  = (const float*)d_in[2];
  const float* Wd  = (const float*)d_in[3];
  const float* mem = (const float*)d_in[4];
  float* outp = (float*)d_out;

  unsigned short* PRhi = (unsigned short*)d_ws;   // [192][768] bf16
  unsigned short* PRlo = PRhi + 192 * 768;        // [192][768] bf16

  precompute_pr<<<32, 768, 0, stream>>>(Wt, Wd, mem, PRhi, PRlo);
  const int B = in_sizes[1];   // 32768
  fused_mfma<<<B / 64, 256, 0, stream>>>(feat, PRhi, PRlo, outp);
}